// Round 8
// baseline (889.914 us; speedup 1.0000x reference)
//
#include <hip/hip_runtime.h>
#include <stdint.h>
#include <stddef.h>

#define B_ 4
#define S_ 2048
#define D_ 1024
#define H_ 16
#define HD_ 64

// exp(x/8) = 2^(x*0.125*log2(e)); folded into the Q projection output.
#define QSCALE 0.18033688f

typedef __bf16 bf16;
typedef __bf16 bf16x8 __attribute__((ext_vector_type(8)));
typedef __bf16 bf16x4 __attribute__((ext_vector_type(4)));
typedef float f32x4 __attribute__((ext_vector_type(4)));
typedef float f32x16 __attribute__((ext_vector_type(16)));
typedef uint32_t u32x4 __attribute__((ext_vector_type(4)));

__device__ __forceinline__ f32x4 mfma16(bf16x8 a, bf16x8 b, f32x4 c) {
  return __builtin_amdgcn_mfma_f32_16x16x32_bf16(a, b, c, 0, 0, 0);
}
__device__ __forceinline__ f32x16 mfma32(bf16x8 a, bf16x8 b, f32x16 c) {
  return __builtin_amdgcn_mfma_f32_32x32x16_bf16(a, b, c, 0, 0, 0);
}

__device__ __forceinline__ float fexp2(float x) {
#if __has_builtin(__builtin_amdgcn_exp2f)
  return __builtin_amdgcn_exp2f(x);
#else
  return exp2f(x);
#endif
}

// global -> LDS direct copy, 16B per lane. LDS dst is wave-uniform base
// (HW writes base + lane*16); global src is per-lane.
__device__ __forceinline__ void gload_lds16(const void* g, void* l) {
  __builtin_amdgcn_global_load_lds(
      (__attribute__((address_space(1))) uint32_t*)(uintptr_t)g,
      (__attribute__((address_space(3))) uint32_t*)l, 16, 0, 0);
}

__device__ __forceinline__ uint32_t cvt_pk(float lo, float hi) {
  uint32_t r;
  asm volatile("v_cvt_pk_bf16_f32 %0, %1, %2" : "=v"(r) : "v"(lo), "v"(hi));
  return r;
}

// v_permlane32_swap_b32: a' = lane<32 ? a : b[lane-32]; b' = lane<32 ? a[lane+32] : b
__device__ __forceinline__ void pl_swap(uint32_t& a, uint32_t& b) {
#if __has_builtin(__builtin_amdgcn_permlane32_swap)
  typedef int i32x2_t __attribute__((ext_vector_type(2)));
  i32x2_t r = __builtin_amdgcn_permlane32_swap((int)a, (int)b, false, false);
  a = (uint32_t)r[0];
  b = (uint32_t)r[1];
#else
  uint32_t pa_ = (uint32_t)__shfl_xor((int)a, 32);
  uint32_t pb_ = (uint32_t)__shfl_xor((int)b, 32);
  bool hi_ = (threadIdx.x & 32) != 0;
  uint32_t na = hi_ ? pb_ : a;
  uint32_t nb = hi_ ? b : pa_;
  a = na;
  b = nb;
#endif
}

__device__ __forceinline__ bf16x8 pack4(uint32_t a, uint32_t b, uint32_t c,
                                        uint32_t d) {
  u32x4 v = {a, b, c, d};
  return __builtin_bit_cast(bf16x8, v);
}

// ---------------------------------------------------------------------------
// f32 -> bf16 weight conversion (4 x [1024x1024])
// ---------------------------------------------------------------------------
__global__ __launch_bounds__(256) void convert_w(
    const float* __restrict__ a, const float* __restrict__ b,
    const float* __restrict__ c, const float* __restrict__ d,
    bf16* __restrict__ out) {
  int i = (blockIdx.x * 256 + threadIdx.x) * 4;
  const float* srcs[4] = {a, b, c, d};
#pragma unroll
  for (int w = 0; w < 4; ++w) {
    f32x4 x = *(const f32x4*)(srcs[w] + i);
    bf16x4 v;
    v[0] = (bf16)x[0]; v[1] = (bf16)x[1]; v[2] = (bf16)x[2]; v[3] = (bf16)x[3];
    *(bf16x4*)(out + (size_t)w * (D_ * D_) + i) = v;
  }
}

// ---------------------------------------------------------------------------
// f32 -> bf16 input conversion (one [B*S*D] array), vectorized 8 elems/thread
// ---------------------------------------------------------------------------
__global__ __launch_bounds__(256) void convert_in(const float* __restrict__ in,
                                                  bf16* __restrict__ out) {
  const int n8 = (B_ * S_ * D_) / 8;
  for (int i = blockIdx.x * 256 + threadIdx.x; i < n8; i += gridDim.x * 256) {
    f32x4 x0 = *(const f32x4*)(in + (size_t)i * 8);
    f32x4 x1 = *(const f32x4*)(in + (size_t)i * 8 + 4);
    bf16x8 v;
    v[0] = (bf16)x0[0]; v[1] = (bf16)x0[1]; v[2] = (bf16)x0[2]; v[3] = (bf16)x0[3];
    v[4] = (bf16)x1[0]; v[5] = (bf16)x1[1]; v[6] = (bf16)x1[2]; v[7] = (bf16)x1[3];
    *(bf16x8*)(out + (size_t)i * 8) = v;
  }
}

// ---------------------------------------------------------------------------
// bf16 GEMM: C[8192][1024] = A[8192][1024] @ W[1024][1024]^T + bias
// 128x128 tile, BK=64, 4 waves (2x2). A and W both staged via global_load_lds.
// MODE 0: bf16 head layout [B][H][S][HD], scaled by oscale (Q / K)
// MODE 1: bf16 transposed head layout [B][H][HD][S]  (V)
// MODE 2: f32 row-major [8192][1024] (final output)
// ---------------------------------------------------------------------------
template <int MODE>
__global__ __launch_bounds__(256, 2) void gemm_bf16(
    const bf16* __restrict__ A, const bf16* __restrict__ Wb,
    const float* __restrict__ bias, void* __restrict__ Out, float oscale) {
  __shared__ alignas(128) char lds[32768];  // A: [0,16K)  B: [16K,32K)
  const int tid = threadIdx.x;
  const int lane = tid & 63;
  const int wave = tid >> 6;
  const int m0 = blockIdx.x * 128;
  const int n0 = blockIdx.y * 128;
  const int wr = wave >> 1, wc = wave & 1;

  f32x4 acc[4][4] = {};

  for (int kt = 0; kt < 16; ++kt) {
    const int k0 = kt * 64;
#pragma unroll
    for (int j = 0; j < 4; ++j) {
      int slot = j * 256 + tid;
      int row = slot >> 3, kb = slot & 7;
      gload_lds16(A + (size_t)(m0 + row) * D_ + k0 + ((kb ^ (row & 7)) << 3),
                  lds + j * 4096 + wave * 1024);
    }
#pragma unroll
    for (int j = 0; j < 4; ++j) {
      int slot = j * 256 + tid;
      int row = slot >> 3, kb = slot & 7;
      gload_lds16(Wb + (size_t)(n0 + row) * D_ + k0 + ((kb ^ (row & 7)) << 3),
                  lds + 16384 + j * 4096 + wave * 1024);
    }
    __syncthreads();
#pragma unroll
    for (int ks = 0; ks < 2; ++ks) {
      bf16x8 af[4], bfr[4];
#pragma unroll
      for (int f = 0; f < 4; ++f) {
        int ar = wr * 64 + f * 16 + (lane & 15);
        af[f] = *(const bf16x8*)(lds + ar * 128 +
                                 (((ks * 4 + (lane >> 4)) ^ (ar & 7)) << 4));
        int br = wc * 64 + f * 16 + (lane & 15);
        bfr[f] = *(const bf16x8*)(lds + 16384 + br * 128 +
                                  (((ks * 4 + (lane >> 4)) ^ (br & 7)) << 4));
      }
#pragma unroll
      for (int i = 0; i < 4; ++i)
#pragma unroll
        for (int j = 0; j < 4; ++j)
          acc[i][j] = mfma16(af[i], bfr[j], acc[i][j]);
    }
    __syncthreads();
  }

  // epilogue. C frag mapping: col = lane&15, row = (lane>>4)*4 + r.
#pragma unroll
  for (int j = 0; j < 4; ++j) {
    const int col = n0 + wc * 64 + j * 16 + (lane & 15);
    const float bv_ = bias[col];
    const int h = col >> 6, hd = col & 63;
#pragma unroll
    for (int i = 0; i < 4; ++i) {
      const int row0 = m0 + wr * 64 + i * 16 + ((lane >> 4) << 2);
      if (MODE == 2) {
        float* O = (float*)Out;
#pragma unroll
        for (int r = 0; r < 4; ++r)
          O[(size_t)(row0 + r) * D_ + col] = acc[i][j][r] + bv_;
      } else if (MODE == 0) {  // head layout [B][H][S][HD]
        bf16* O = (bf16*)Out;
#pragma unroll
        for (int r = 0; r < 4; ++r) {
          int row = row0 + r;
          int b = row >> 11, s = row & (S_ - 1);
          O[(((size_t)(b * H_ + h) * S_ + s) << 6) + hd] =
              (bf16)((acc[i][j][r] + bv_) * oscale);
        }
      } else {  // MODE 1: V transposed [B][H][HD][S]; acc rows s-contiguous
        bf16* O = (bf16*)Out;
        int b = row0 >> 11, s0 = row0 & (S_ - 1);
        bf16x4 pk;
#pragma unroll
        for (int r = 0; r < 4; ++r) pk[r] = (bf16)(acc[i][j][r] + bv_);
        *(bf16x4*)(O + ((size_t)(b * H_ + h) * HD_ + hd) * S_ + s0) = pk;
      }
    }
  }
}

// ---------------------------------------------------------------------------
// Attention v7: kv-split for occupancy. Block = 512 thr = 8 waves:
// (qw in [0,4)) x (kvh in {0,1}). Each wave: 64 q (2 q-groups), HALF the kv
// range (16 tiles of 64 kv). Each kvh half double-buffers its own 16KB tile
// -> 64KB LDS, 2 blocks/CU, 4 waves/SIMD (2x v6's overlap capacity) with
// per-work LDS/VALU/TRANS unchanged. No-max softmax is linear in (oacc,den)
// so halves merge exactly via LDS at the end (tile region is dead by then).
// Grid 512 1D: bh = bid&63 -> XCD co-location. Dual-pipe tile body from v6.
// ---------------------------------------------------------------------------
__global__ __launch_bounds__(512, 4) void attn_kernel(
    const bf16* __restrict__ Qh, const bf16* __restrict__ Kh,
    const bf16* __restrict__ Vt, bf16* __restrict__ AO) {
  // per kvh half: K frags 0..7 (kb*4+ks), V frags 8..15 ((kslot*2)+ht), 1KB
  // each; double buffered. half base = kvh*32768, buffer base = cur*16384.
  __shared__ alignas(128) char lds[65536];
  const int tid = threadIdx.x, lane = tid & 63, wave = tid >> 6;
  const int hi = lane >> 5, l31 = lane & 31;
  const int kvh = wave & 1, qw = wave >> 1;
  const int bid = blockIdx.x;
  const int bh = bid & 63;   // XCD co-location: xcd = bid%8 = bh%8
  const int qb = bid >> 6;   // [0,8)
  const int q0 = qb * 256 + qw * 64;
  const bf16* Qb = Qh + (size_t)bh * S_ * HD_;
  const bf16* Kb = Kh + (size_t)bh * S_ * HD_;
  const bf16* Vb = Vt + (size_t)bh * HD_ * S_;

  // Q B-frags (col q = l31, k = hd = ks*16 + hi*8 + j); 2 q-groups.
  bf16x8 qf[2][4];
#pragma unroll
  for (int qg = 0; qg < 2; ++qg)
#pragma unroll
    for (int ks = 0; ks < 4; ++ks)
      qf[qg][ks] = *(const bf16x8*)(Qb + (size_t)(q0 + qg * 32 + l31) * HD_ +
                                    ks * 16 + hi * 8);

  // staging: within a kvh group (4 waves), wave qw stages frags
  // {qw, 4+qw, 8+qw, 12+qw} of its half's tile. kv base = kvh*1024.
  const bf16* gs[4];
  int lo_[4], ginc[4];
#pragma unroll
  for (int j = 0; j < 4; ++j) {
    int f = j * 4 + qw;
    lo_[j] = kvh * 32768 + f * 1024;
    if (f < 8) {  // K frag: kb = f>>2, ks = f&3; row = kv, col = hd
      gs[j] = Kb + (size_t)(kvh * 1024 + (f >> 2) * 32 + l31) * HD_ +
              (f & 3) * 16 + hi * 8;
      ginc[j] = 64 * HD_;
    } else {  // V frag g=f-8: ht = g&1, kslot = g>>1; row = hd, col = kv
      int g = f - 8;
      gs[j] = Vb + (size_t)((g & 1) * 32 + l31) * S_ + kvh * 1024 +
              (g >> 1) * 16 + hi * 8;
      ginc[j] = 64;
    }
  }

  f32x16 oacc[2][2] = {};     // [qg][ht]
  float dl[2] = {0.f, 0.f};   // per-lane den partial per q-group

  // prologue: stage tile 0 of this half into buf 0
#pragma unroll
  for (int j = 0; j < 4; ++j) {
    gload_lds16(gs[j], &lds[lo_[j]]);
    gs[j] += ginc[j];
  }
  __syncthreads();

  for (int t = 0; t < 16; ++t) {
    const int cur = t & 1;
    if (t < 15) {  // prefetch next tile; latency hides under compute
#pragma unroll
      for (int j = 0; j < 4; ++j) {
        gload_lds16(gs[j], &lds[lo_[j] + ((cur ^ 1) << 14)]);
        gs[j] += ginc[j];
      }
    }
    const char* kbuf = lds + kvh * 32768 + cur * 16384;
    const char* vbuf = kbuf + 8192;

    // ---- QK issue for BOTH kv-blocks (16 mfma) ----
    f32x16 s[2][2];  // [kb][qg]
    s[0][0] = (f32x16){}; s[0][1] = (f32x16){};
    s[1][0] = (f32x16){}; s[1][1] = (f32x16){};
    __builtin_amdgcn_s_setprio(1);
#pragma unroll
    for (int kb = 0; kb < 2; ++kb)
#pragma unroll
      for (int ks = 0; ks < 4; ++ks) {
        bf16x8 kf = *(const bf16x8*)(kbuf + (kb * 4 + ks) * 1024 + lane * 16);
        s[kb][0] = mfma32(kf, qf[0][ks], s[kb][0]);
        s[kb][1] = mfma32(kf, qf[1][ks], s[kb][1]);
      }
    __builtin_amdgcn_s_setprio(0);

    // ---- per kv-block: softmax (VALU/TRANS) then PV (MFMA); softmax(kb1)
    // overlaps PV(kb0), softmax(kb0) overlaps QK tail. ----
#pragma unroll
    for (int kb = 0; kb < 2; ++kb) {
      bf16x8 pa[2][2];
#pragma unroll
      for (int qg = 0; qg < 2; ++qg) {
        float e[16];
#pragma unroll
        for (int r = 0; r < 16; ++r) e[r] = fexp2(s[kb][qg][r]);
        {
          float a0 = e[0] + e[1], a1 = e[2] + e[3], a2 = e[4] + e[5],
                a3 = e[6] + e[7], a4 = e[8] + e[9], a5 = e[10] + e[11],
                a6 = e[12] + e[13], a7 = e[14] + e[15];
          float b0 = a0 + a1, b1 = a2 + a3, b2 = a4 + a5, b3 = a6 + a7;
          dl[qg] += (b0 + b1) + (b2 + b3);
        }
        uint32_t w0 = cvt_pk(e[0], e[1]), w1 = cvt_pk(e[2], e[3]),
                 w2 = cvt_pk(e[4], e[5]), w3 = cvt_pk(e[6], e[7]),
                 w4 = cvt_pk(e[8], e[9]), w5 = cvt_pk(e[10], e[11]),
                 w6 = cvt_pk(e[12], e[13]), w7 = cvt_pk(e[14], e[15]);
        pl_swap(w0, w2);
        pl_swap(w1, w3);
        pl_swap(w4, w6);
        pl_swap(w5, w7);
        pa[qg][0] = pack4(w0, w1, w2, w3);  // kv 0..15 of this 32-block
        pa[qg][1] = pack4(w4, w5, w6, w7);  // kv 16..31
      }
      __builtin_amdgcn_s_setprio(1);
#pragma unroll
      for (int ht = 0; ht < 2; ++ht) {
        bf16x8 vf0 =
            *(const bf16x8*)(vbuf + ((kb * 2 + 0) * 2 + ht) * 1024 + lane * 16);
        oacc[0][ht] = mfma32(pa[0][0], vf0, oacc[0][ht]);
        oacc[1][ht] = mfma32(pa[1][0], vf0, oacc[1][ht]);
        bf16x8 vf1 =
            *(const bf16x8*)(vbuf + ((kb * 2 + 1) * 2 + ht) * 1024 + lane * 16);
        oacc[0][ht] = mfma32(pa[0][1], vf1, oacc[0][ht]);
        oacc[1][ht] = mfma32(pa[1][1], vf1, oacc[1][ht]);
      }
      __builtin_amdgcn_s_setprio(0);
    }
    __syncthreads();  // next tile staged; cur buffer free for overwrite
  }

  // ---- combine kv halves through (now dead) tile LDS: 2 phases (per qg).
  // kvh=1 waves publish oacc[qg][*] (32 f32/lane) + dl[qg] (1 f32/lane);
  // kvh=0 waves add, normalize, and write AO.
  float dfin[2] = {1.f, 1.f};
#pragma unroll
  for (int qg = 0; qg < 2; ++qg) {
    float* base = (float*)lds + qw * 2112;  // 33 * 64 floats per qw
    if (kvh == 1) {
#pragma unroll
      for (int r = 0; r < 16; ++r) {
        base[r * 64 + lane] = oacc[qg][0][r];
        base[(16 + r) * 64 + lane] = oacc[qg][1][r];
      }
      base[32 * 64 + lane] = dl[qg];
    }
    __syncthreads();
    if (kvh == 0) {
#pragma unroll
      for (int r = 0; r < 16; ++r) {
        oacc[qg][0][r] += base[r * 64 + lane];
        oacc[qg][1][r] += base[(16 + r) * 64 + lane];
      }
      float d = dl[qg] + base[32 * 64 + lane];
      d += __shfl_xor(d, 32);
      dfin[qg] = 1.0f / d;
    }
    __syncthreads();
  }

  if (kvh == 0) {
    const int b = bh >> 4, h = bh & 15;
#pragma unroll
    for (int qg = 0; qg < 2; ++qg) {
      float rden = dfin[qg];
#pragma unroll
      for (int r = 0; r < 16; ++r) {
        int qr = (r & 3) + 8 * (r >> 2) + 4 * hi;  // q_local for this row
        float dr = __shfl(rden, qr);               // lane qr holds rden(q=qr)
        size_t base2 = ((size_t)(b * S_ + q0 + qg * 32 + qr)) * D_ + h * 64;
        AO[base2 + l31] = (bf16)(oacc[qg][0][r] * dr);
        AO[base2 + 32 + l31] = (bf16)(oacc[qg][1][r] * dr);
      }
    }
  }
}

// ---------------------------------------------------------------------------
extern "C" void kernel_launch(void* const* d_in, const int* in_sizes, int n_in,
                              void* d_out, int out_size, void* d_ws,
                              size_t ws_size, hipStream_t stream) {
  (void)in_sizes; (void)n_in; (void)out_size; (void)ws_size;
  const float* q  = (const float*)d_in[0];
  const float* k  = (const float*)d_in[1];
  const float* v  = (const float*)d_in[2];
  const float* Wq = (const float*)d_in[3];
  const float* bq = (const float*)d_in[4];
  const float* Wk = (const float*)d_in[5];
  const float* bk = (const float*)d_in[6];
  const float* Wv = (const float*)d_in[7];
  const float* bv = (const float*)d_in[8];
  const float* Wo = (const float*)d_in[9];
  const float* bo = (const float*)d_in[10];

  bf16* ws = (bf16*)d_ws;
  const size_t WSZ = (size_t)D_ * D_;      // 1M elems per weight
  const size_t TSZ = (size_t)B_ * S_ * D_; // 8.39M elems per tensor
  bf16* Wqb = ws;
  bf16* Wkb = ws + WSZ;
  bf16* Wvb = ws + 2 * WSZ;
  bf16* Wob = ws + 3 * WSZ;
  bf16* Abf = ws + 4 * WSZ;  // bf16 copy of current input; later aliased by AO
  bf16* Qh  = Abf + TSZ;
  bf16* Kh  = Qh + TSZ;
  bf16* Vt  = Kh + TSZ;
  bf16* AO  = Abf;  // Abf dead after the 3rd projection GEMM

  convert_w<<<dim3(1024), dim3(256), 0, stream>>>(Wq, Wk, Wv, Wo, ws);
  dim3 gg(64, 8), bb(256);
  convert_in<<<dim3(2048), bb, 0, stream>>>(q, Abf);
  gemm_bf16<0><<<gg, bb, 0, stream>>>(Abf, Wqb, bq, Qh, QSCALE);
  convert_in<<<dim3(2048), bb, 0, stream>>>(k, Abf);
  gemm_bf16<0><<<gg, bb, 0, stream>>>(Abf, Wkb, bk, Kh, 1.0f);
  convert_in<<<dim3(2048), bb, 0, stream>>>(v, Abf);
  gemm_bf16<1><<<gg, bb, 0, stream>>>(Abf, Wvb, bv, Vt, 1.0f);
  attn_kernel<<<dim3(512), dim3(512), 0, stream>>>(Qh, Kh, Vt, AO);
  gemm_bf16<2><<<gg, bb, 0, stream>>>(AO, Wob, bo, d_out, 1.0f);
}

// Round 9
// 200.403 us; speedup vs baseline: 4.4406x; 4.4406x over previous
//
#include <hip/hip_runtime.h>
#include <stdint.h>
#include <stddef.h>

#define B_ 4
#define S_ 2048
#define D_ 1024
#define H_ 16
#define HD_ 64

// exp(x/8) = 2^(x*0.125*log2(e)); folded into the Q projection output.
#define QSCALE 0.18033688f

typedef __bf16 bf16;
typedef __bf16 bf16x8 __attribute__((ext_vector_type(8)));
typedef __bf16 bf16x4 __attribute__((ext_vector_type(4)));
typedef float f32x4 __attribute__((ext_vector_type(4)));
typedef float f32x16 __attribute__((ext_vector_type(16)));
typedef uint32_t u32x4 __attribute__((ext_vector_type(4)));

__device__ __forceinline__ f32x4 mfma16(bf16x8 a, bf16x8 b, f32x4 c) {
  return __builtin_amdgcn_mfma_f32_16x16x32_bf16(a, b, c, 0, 0, 0);
}
__device__ __forceinline__ f32x16 mfma32(bf16x8 a, bf16x8 b, f32x16 c) {
  return __builtin_amdgcn_mfma_f32_32x32x16_bf16(a, b, c, 0, 0, 0);
}

__device__ __forceinline__ float fexp2(float x) {
#if __has_builtin(__builtin_amdgcn_exp2f)
  return __builtin_amdgcn_exp2f(x);
#else
  return exp2f(x);
#endif
}

// global -> LDS direct copy, 16B per lane. LDS dst is wave-uniform base
// (HW writes base + lane*16); global src is per-lane.
__device__ __forceinline__ void gload_lds16(const void* g, void* l) {
  __builtin_amdgcn_global_load_lds(
      (__attribute__((address_space(1))) uint32_t*)(uintptr_t)g,
      (__attribute__((address_space(3))) uint32_t*)l, 16, 0, 0);
}

__device__ __forceinline__ uint32_t cvt_pk(float lo, float hi) {
  uint32_t r;
  asm volatile("v_cvt_pk_bf16_f32 %0, %1, %2" : "=v"(r) : "v"(lo), "v"(hi));
  return r;
}

// v_permlane32_swap_b32: a' = lane<32 ? a : b[lane-32]; b' = lane<32 ? a[lane+32] : b
__device__ __forceinline__ void pl_swap(uint32_t& a, uint32_t& b) {
#if __has_builtin(__builtin_amdgcn_permlane32_swap)
  typedef int i32x2_t __attribute__((ext_vector_type(2)));
  i32x2_t r = __builtin_amdgcn_permlane32_swap((int)a, (int)b, false, false);
  a = (uint32_t)r[0];
  b = (uint32_t)r[1];
#else
  uint32_t pa_ = (uint32_t)__shfl_xor((int)a, 32);
  uint32_t pb_ = (uint32_t)__shfl_xor((int)b, 32);
  bool hi_ = (threadIdx.x & 32) != 0;
  uint32_t na = hi_ ? pb_ : a;
  uint32_t nb = hi_ ? b : pa_;
  a = na;
  b = nb;
#endif
}

__device__ __forceinline__ bf16x8 pack4(uint32_t a, uint32_t b, uint32_t c,
                                        uint32_t d) {
  u32x4 v = {a, b, c, d};
  return __builtin_bit_cast(bf16x8, v);
}

// ---------------------------------------------------------------------------
// f32 -> bf16 weight conversion (4 x [1024x1024])
// ---------------------------------------------------------------------------
__global__ __launch_bounds__(256) void convert_w(
    const float* __restrict__ a, const float* __restrict__ b,
    const float* __restrict__ c, const float* __restrict__ d,
    bf16* __restrict__ out) {
  int i = (blockIdx.x * 256 + threadIdx.x) * 4;
  const float* srcs[4] = {a, b, c, d};
#pragma unroll
  for (int w = 0; w < 4; ++w) {
    f32x4 x = *(const f32x4*)(srcs[w] + i);
    bf16x4 v;
    v[0] = (bf16)x[0]; v[1] = (bf16)x[1]; v[2] = (bf16)x[2]; v[3] = (bf16)x[3];
    *(bf16x4*)(out + (size_t)w * (D_ * D_) + i) = v;
  }
}

// ---------------------------------------------------------------------------
// f32 -> bf16 input conversion (one [B*S*D] array), vectorized 8 elems/thread
// ---------------------------------------------------------------------------
__global__ __launch_bounds__(256) void convert_in(const float* __restrict__ in,
                                                  bf16* __restrict__ out) {
  const int n8 = (B_ * S_ * D_) / 8;
  for (int i = blockIdx.x * 256 + threadIdx.x; i < n8; i += gridDim.x * 256) {
    f32x4 x0 = *(const f32x4*)(in + (size_t)i * 8);
    f32x4 x1 = *(const f32x4*)(in + (size_t)i * 8 + 4);
    bf16x8 v;
    v[0] = (bf16)x0[0]; v[1] = (bf16)x0[1]; v[2] = (bf16)x0[2]; v[3] = (bf16)x0[3];
    v[4] = (bf16)x1[0]; v[5] = (bf16)x1[1]; v[6] = (bf16)x1[2]; v[7] = (bf16)x1[3];
    *(bf16x8*)(out + (size_t)i * 8) = v;
  }
}

// ---------------------------------------------------------------------------
// bf16 GEMM: C[8192][1024] = A[8192][1024] @ W[1024][1024]^T + bias
// 128x128 tile, BK=64, 4 waves (2x2). A and W both staged via global_load_lds.
// MODE 0: bf16 head layout [B][H][S][HD], scaled by oscale (Q / K)
// MODE 1: bf16 transposed head layout [B][H][HD][S]  (V)
// MODE 2: f32 row-major [8192][1024] (final output)
// ---------------------------------------------------------------------------
template <int MODE>
__global__ __launch_bounds__(256, 2) void gemm_bf16(
    const bf16* __restrict__ A, const bf16* __restrict__ Wb,
    const float* __restrict__ bias, void* __restrict__ Out, float oscale) {
  __shared__ alignas(128) char lds[32768];  // A: [0,16K)  B: [16K,32K)
  const int tid = threadIdx.x;
  const int lane = tid & 63;
  const int wave = tid >> 6;
  const int m0 = blockIdx.x * 128;
  const int n0 = blockIdx.y * 128;
  const int wr = wave >> 1, wc = wave & 1;

  f32x4 acc[4][4] = {};

  for (int kt = 0; kt < 16; ++kt) {
    const int k0 = kt * 64;
#pragma unroll
    for (int j = 0; j < 4; ++j) {
      int slot = j * 256 + tid;
      int row = slot >> 3, kb = slot & 7;
      gload_lds16(A + (size_t)(m0 + row) * D_ + k0 + ((kb ^ (row & 7)) << 3),
                  lds + j * 4096 + wave * 1024);
    }
#pragma unroll
    for (int j = 0; j < 4; ++j) {
      int slot = j * 256 + tid;
      int row = slot >> 3, kb = slot & 7;
      gload_lds16(Wb + (size_t)(n0 + row) * D_ + k0 + ((kb ^ (row & 7)) << 3),
                  lds + 16384 + j * 4096 + wave * 1024);
    }
    __syncthreads();
#pragma unroll
    for (int ks = 0; ks < 2; ++ks) {
      bf16x8 af[4], bfr[4];
#pragma unroll
      for (int f = 0; f < 4; ++f) {
        int ar = wr * 64 + f * 16 + (lane & 15);
        af[f] = *(const bf16x8*)(lds + ar * 128 +
                                 (((ks * 4 + (lane >> 4)) ^ (ar & 7)) << 4));
        int br = wc * 64 + f * 16 + (lane & 15);
        bfr[f] = *(const bf16x8*)(lds + 16384 + br * 128 +
                                  (((ks * 4 + (lane >> 4)) ^ (br & 7)) << 4));
      }
#pragma unroll
      for (int i = 0; i < 4; ++i)
#pragma unroll
        for (int j = 0; j < 4; ++j)
          acc[i][j] = mfma16(af[i], bfr[j], acc[i][j]);
    }
    __syncthreads();
  }

  // epilogue. C frag mapping: col = lane&15, row = (lane>>4)*4 + r.
#pragma unroll
  for (int j = 0; j < 4; ++j) {
    const int col = n0 + wc * 64 + j * 16 + (lane & 15);
    const float bv_ = bias[col];
    const int h = col >> 6, hd = col & 63;
#pragma unroll
    for (int i = 0; i < 4; ++i) {
      const int row0 = m0 + wr * 64 + i * 16 + ((lane >> 4) << 2);
      if (MODE == 2) {
        float* O = (float*)Out;
#pragma unroll
        for (int r = 0; r < 4; ++r)
          O[(size_t)(row0 + r) * D_ + col] = acc[i][j][r] + bv_;
      } else if (MODE == 0) {  // head layout [B][H][S][HD]
        bf16* O = (bf16*)Out;
#pragma unroll
        for (int r = 0; r < 4; ++r) {
          int row = row0 + r;
          int b = row >> 11, s = row & (S_ - 1);
          O[(((size_t)(b * H_ + h) * S_ + s) << 6) + hd] =
              (bf16)((acc[i][j][r] + bv_) * oscale);
        }
      } else {  // MODE 1: V transposed [B][H][HD][S]; acc rows s-contiguous
        bf16* O = (bf16*)Out;
        int b = row0 >> 11, s0 = row0 & (S_ - 1);
        bf16x4 pk;
#pragma unroll
        for (int r = 0; r < 4; ++r) pk[r] = (bf16)(acc[i][j][r] + bv_);
        *(bf16x4*)(O + ((size_t)(b * H_ + h) * HD_ + hd) * S_ + s0) = pk;
      }
    }
  }
}

// ---------------------------------------------------------------------------
// Attention v8: kv-split for occupancy, register budget respected.
// Block = 512 thr = 8 waves: (qw in [0,4)) x (kvh in {0,1}). Each wave: 64 q
// (2 q-groups), HALF the kv range (16 tiles of 64 kv). __launch_bounds__(512,2)
// -> 2 blocks/CU x 8 waves = 4 waves/SIMD, VGPR cap 128 (v5-shape body
// measured 112 -> no spills). Per-kb body: QK -> softmax -> PV; cross-wave
// overlap fills both pipes at 4 waves/SIMD. 64KB LDS (per-half double
// buffer). Linear no-max softmax -> halves combine exactly via dead tile LDS.
// Grid 512 1D: bh = bid&63 -> XCD co-location.
// ---------------------------------------------------------------------------
__global__ __launch_bounds__(512, 2) void attn_kernel(
    const bf16* __restrict__ Qh, const bf16* __restrict__ Kh,
    const bf16* __restrict__ Vt, bf16* __restrict__ AO) {
  // per kvh half: K frags 0..7 (kb*4+ks), V frags 8..15 ((kslot*2)+ht), 1KB
  // each; double buffered. half base = kvh*32768, buffer base = cur*16384.
  __shared__ alignas(128) char lds[65536];
  const int tid = threadIdx.x, lane = tid & 63, wave = tid >> 6;
  const int hi = lane >> 5, l31 = lane & 31;
  const int kvh = wave & 1, qw = wave >> 1;
  const int bid = blockIdx.x;
  const int bh = bid & 63;   // XCD co-location: xcd = bid%8 = bh%8
  const int qb = bid >> 6;   // [0,8)
  const int q0 = qb * 256 + qw * 64;
  const bf16* Qb = Qh + (size_t)bh * S_ * HD_;
  const bf16* Kb = Kh + (size_t)bh * S_ * HD_;
  const bf16* Vb = Vt + (size_t)bh * HD_ * S_;

  // Q B-frags (col q = l31, k = hd = ks*16 + hi*8 + j); 2 q-groups.
  bf16x8 qf[2][4];
#pragma unroll
  for (int qg = 0; qg < 2; ++qg)
#pragma unroll
    for (int ks = 0; ks < 4; ++ks)
      qf[qg][ks] = *(const bf16x8*)(Qb + (size_t)(q0 + qg * 32 + l31) * HD_ +
                                    ks * 16 + hi * 8);

  // staging: within a kvh group (4 waves), wave qw stages frags
  // {qw, 4+qw, 8+qw, 12+qw} of its half's tile. kv base = kvh*1024.
  const bf16* gs[4];
  int lo_[4], ginc[4];
#pragma unroll
  for (int j = 0; j < 4; ++j) {
    int f = j * 4 + qw;
    lo_[j] = kvh * 32768 + f * 1024;
    if (f < 8) {  // K frag: kb = f>>2, ks = f&3; row = kv, col = hd
      gs[j] = Kb + (size_t)(kvh * 1024 + (f >> 2) * 32 + l31) * HD_ +
              (f & 3) * 16 + hi * 8;
      ginc[j] = 64 * HD_;
    } else {  // V frag g=f-8: ht = g&1, kslot = g>>1; row = hd, col = kv
      int g = f - 8;
      gs[j] = Vb + (size_t)((g & 1) * 32 + l31) * S_ + kvh * 1024 +
              (g >> 1) * 16 + hi * 8;
      ginc[j] = 64;
    }
  }

  f32x16 oacc[2][2] = {};     // [qg][ht]
  float dl[2] = {0.f, 0.f};   // per-lane den partial per q-group

  // prologue: stage tile 0 of this half into buf 0
#pragma unroll
  for (int j = 0; j < 4; ++j) {
    gload_lds16(gs[j], &lds[lo_[j]]);
    gs[j] += ginc[j];
  }
  __syncthreads();

  for (int t = 0; t < 16; ++t) {
    const int cur = t & 1;
    if (t < 15) {  // prefetch next tile; latency hides under compute
#pragma unroll
      for (int j = 0; j < 4; ++j) {
        gload_lds16(gs[j], &lds[lo_[j] + ((cur ^ 1) << 14)]);
        gs[j] += ginc[j];
      }
    }
    const char* kbuf = lds + kvh * 32768 + cur * 16384;
    const char* vbuf = kbuf + 8192;

    // per kv-block: QK (8 mfma) -> softmax -> PV (8 mfma). At 4 waves/SIMD,
    // cross-wave interleave fills MFMA and VALU/TRANS pipes.
#pragma unroll
    for (int kb = 0; kb < 2; ++kb) {
      f32x16 s0 = {}, s1 = {};
      __builtin_amdgcn_s_setprio(1);
#pragma unroll
      for (int ks = 0; ks < 4; ++ks) {
        bf16x8 kf = *(const bf16x8*)(kbuf + (kb * 4 + ks) * 1024 + lane * 16);
        s0 = mfma32(kf, qf[0][ks], s0);
        s1 = mfma32(kf, qf[1][ks], s1);
      }
      __builtin_amdgcn_s_setprio(0);
      bf16x8 pa[2][2];
#pragma unroll
      for (int qg = 0; qg < 2; ++qg) {
        f32x16 s = qg ? s1 : s0;
        float e[16];
#pragma unroll
        for (int r = 0; r < 16; ++r) e[r] = fexp2(s[r]);
        {
          float a0 = e[0] + e[1], a1 = e[2] + e[3], a2 = e[4] + e[5],
                a3 = e[6] + e[7], a4 = e[8] + e[9], a5 = e[10] + e[11],
                a6 = e[12] + e[13], a7 = e[14] + e[15];
          float b0 = a0 + a1, b1 = a2 + a3, b2 = a4 + a5, b3 = a6 + a7;
          dl[qg] += (b0 + b1) + (b2 + b3);
        }
        uint32_t w0 = cvt_pk(e[0], e[1]), w1 = cvt_pk(e[2], e[3]),
                 w2 = cvt_pk(e[4], e[5]), w3 = cvt_pk(e[6], e[7]),
                 w4 = cvt_pk(e[8], e[9]), w5 = cvt_pk(e[10], e[11]),
                 w6 = cvt_pk(e[12], e[13]), w7 = cvt_pk(e[14], e[15]);
        pl_swap(w0, w2);
        pl_swap(w1, w3);
        pl_swap(w4, w6);
        pl_swap(w5, w7);
        pa[qg][0] = pack4(w0, w1, w2, w3);  // kv 0..15 of this 32-block
        pa[qg][1] = pack4(w4, w5, w6, w7);  // kv 16..31
      }
      __builtin_amdgcn_s_setprio(1);
#pragma unroll
      for (int ht = 0; ht < 2; ++ht) {
        bf16x8 vf0 =
            *(const bf16x8*)(vbuf + ((kb * 2 + 0) * 2 + ht) * 1024 + lane * 16);
        oacc[0][ht] = mfma32(pa[0][0], vf0, oacc[0][ht]);
        oacc[1][ht] = mfma32(pa[1][0], vf0, oacc[1][ht]);
        bf16x8 vf1 =
            *(const bf16x8*)(vbuf + ((kb * 2 + 1) * 2 + ht) * 1024 + lane * 16);
        oacc[0][ht] = mfma32(pa[0][1], vf1, oacc[0][ht]);
        oacc[1][ht] = mfma32(pa[1][1], vf1, oacc[1][ht]);
      }
      __builtin_amdgcn_s_setprio(0);
    }
    __syncthreads();  // next tile staged; cur buffer free for overwrite
  }

  // ---- combine kv halves through (now dead) tile LDS: 2 phases (per qg).
  // kvh=1 waves publish oacc[qg][*] (32 f32/lane) + dl[qg] (1 f32/lane);
  // kvh=0 waves add, normalize, and write AO.
  float dfin[2] = {1.f, 1.f};
#pragma unroll
  for (int qg = 0; qg < 2; ++qg) {
    float* base = (float*)lds + qw * 2112;  // 33 * 64 floats per qw
    if (kvh == 1) {
#pragma unroll
      for (int r = 0; r < 16; ++r) {
        base[r * 64 + lane] = oacc[qg][0][r];
        base[(16 + r) * 64 + lane] = oacc[qg][1][r];
      }
      base[32 * 64 + lane] = dl[qg];
    }
    __syncthreads();
    if (kvh == 0) {
#pragma unroll
      for (int r = 0; r < 16; ++r) {
        oacc[qg][0][r] += base[r * 64 + lane];
        oacc[qg][1][r] += base[(16 + r) * 64 + lane];
      }
      float d = dl[qg] + base[32 * 64 + lane];
      d += __shfl_xor(d, 32);
      dfin[qg] = 1.0f / d;
    }
    __syncthreads();
  }

  if (kvh == 0) {
    const int b = bh >> 4, h = bh & 15;
#pragma unroll
    for (int qg = 0; qg < 2; ++qg) {
      float rden = dfin[qg];
#pragma unroll
      for (int r = 0; r < 16; ++r) {
        int qr = (r & 3) + 8 * (r >> 2) + 4 * hi;  // q_local for this row
        float dr = __shfl(rden, qr);               // lane qr holds rden(q=qr)
        size_t base2 = ((size_t)(b * S_ + q0 + qg * 32 + qr)) * D_ + h * 64;
        AO[base2 + l31] = (bf16)(oacc[qg][0][r] * dr);
        AO[base2 + 32 + l31] = (bf16)(oacc[qg][1][r] * dr);
      }
    }
  }
}

// ---------------------------------------------------------------------------
extern "C" void kernel_launch(void* const* d_in, const int* in_sizes, int n_in,
                              void* d_out, int out_size, void* d_ws,
                              size_t ws_size, hipStream_t stream) {
  (void)in_sizes; (void)n_in; (void)out_size; (void)ws_size;
  const float* q  = (const float*)d_in[0];
  const float* k  = (const float*)d_in[1];
  const float* v  = (const float*)d_in[2];
  const float* Wq = (const float*)d_in[3];
  const float* bq = (const float*)d_in[4];
  const float* Wk = (const float*)d_in[5];
  const float* bk = (const float*)d_in[6];
  const float* Wv = (const float*)d_in[7];
  const float* bv = (const float*)d_in[8];
  const float* Wo = (const float*)d_in[9];
  const float* bo = (const float*)d_in[10];

  bf16* ws = (bf16*)d_ws;
  const size_t WSZ = (size_t)D_ * D_;      // 1M elems per weight
  const size_t TSZ = (size_t)B_ * S_ * D_; // 8.39M elems per tensor
  bf16* Wqb = ws;
  bf16* Wkb = ws + WSZ;
  bf16* Wvb = ws + 2 * WSZ;
  bf16* Wob = ws + 3 * WSZ;
  bf16* Abf = ws + 4 * WSZ;  // bf16 copy of current input; later aliased by AO
  bf16* Qh  = Abf + TSZ;
  bf16* Kh  = Qh + TSZ;
  bf16* Vt  = Kh + TSZ;
  bf16* AO  = Abf;  // Abf dead after the 3rd projection GEMM

  convert_w<<<dim3(1024), dim3(256), 0, stream>>>(Wq, Wk, Wv, Wo, ws);
  dim3 gg(64, 8), bb(256);
  convert_in<<<dim3(2048), bb, 0, stream>>>(q, Abf);
  gemm_bf16<0><<<gg, bb, 0, stream>>>(Abf, Wqb, bq, Qh, QSCALE);
  convert_in<<<dim3(2048), bb, 0, stream>>>(k, Abf);
  gemm_bf16<0><<<gg, bb, 0, stream>>>(Abf, Wkb, bk, Kh, 1.0f);
  convert_in<<<dim3(2048), bb, 0, stream>>>(v, Abf);
  gemm_bf16<1><<<gg, bb, 0, stream>>>(Abf, Wvb, bv, Vt, 1.0f);
  attn_kernel<<<dim3(512), dim3(512), 0, stream>>>(Qh, Kh, Vt, AO);
  gemm_bf16<2><<<gg, bb, 0, stream>>>(AO, Wob, bo, d_out, 1.0f);
}

// Round 10
// 197.608 us; speedup vs baseline: 4.5034x; 1.0141x over previous
//
#include <hip/hip_runtime.h>
#include <stdint.h>
#include <stddef.h>

#define B_ 4
#define S_ 2048
#define D_ 1024
#define H_ 16
#define HD_ 64

// exp(x/8) = 2^(x*0.125*log2(e)); folded into the Q projection output.
#define QSCALE 0.18033688f

typedef __bf16 bf16;
typedef __bf16 bf16x8 __attribute__((ext_vector_type(8)));
typedef __bf16 bf16x4 __attribute__((ext_vector_type(4)));
typedef float f32x4 __attribute__((ext_vector_type(4)));
typedef float f32x16 __attribute__((ext_vector_type(16)));
typedef uint32_t u32x4 __attribute__((ext_vector_type(4)));

__device__ __forceinline__ f32x4 mfma16(bf16x8 a, bf16x8 b, f32x4 c) {
  return __builtin_amdgcn_mfma_f32_16x16x32_bf16(a, b, c, 0, 0, 0);
}
__device__ __forceinline__ f32x16 mfma32(bf16x8 a, bf16x8 b, f32x16 c) {
  return __builtin_amdgcn_mfma_f32_32x32x16_bf16(a, b, c, 0, 0, 0);
}

__device__ __forceinline__ float fexp2(float x) {
#if __has_builtin(__builtin_amdgcn_exp2f)
  return __builtin_amdgcn_exp2f(x);
#else
  return exp2f(x);
#endif
}

// global -> LDS direct copy, 16B per lane. LDS dst is wave-uniform base
// (HW writes base + lane*16); global src is per-lane.
__device__ __forceinline__ void gload_lds16(const void* g, void* l) {
  __builtin_amdgcn_global_load_lds(
      (__attribute__((address_space(1))) uint32_t*)(uintptr_t)g,
      (__attribute__((address_space(3))) uint32_t*)l, 16, 0, 0);
}

__device__ __forceinline__ uint32_t cvt_pk(float lo, float hi) {
  uint32_t r;
  asm volatile("v_cvt_pk_bf16_f32 %0, %1, %2" : "=v"(r) : "v"(lo), "v"(hi));
  return r;
}

// v_permlane32_swap_b32: a' = lane<32 ? a : b[lane-32]; b' = lane<32 ? a[lane+32] : b
__device__ __forceinline__ void pl_swap(uint32_t& a, uint32_t& b) {
#if __has_builtin(__builtin_amdgcn_permlane32_swap)
  typedef int i32x2_t __attribute__((ext_vector_type(2)));
  i32x2_t r = __builtin_amdgcn_permlane32_swap((int)a, (int)b, false, false);
  a = (uint32_t)r[0];
  b = (uint32_t)r[1];
#else
  uint32_t pa_ = (uint32_t)__shfl_xor((int)a, 32);
  uint32_t pb_ = (uint32_t)__shfl_xor((int)b, 32);
  bool hi_ = (threadIdx.x & 32) != 0;
  uint32_t na = hi_ ? pb_ : a;
  uint32_t nb = hi_ ? b : pa_;
  a = na;
  b = nb;
#endif
}

__device__ __forceinline__ bf16x8 pack4(uint32_t a, uint32_t b, uint32_t c,
                                        uint32_t d) {
  u32x4 v = {a, b, c, d};
  return __builtin_bit_cast(bf16x8, v);
}

// ---------------------------------------------------------------------------
// f32 -> bf16 weight conversion (4 x [1024x1024])
// ---------------------------------------------------------------------------
__global__ __launch_bounds__(256) void convert_w(
    const float* __restrict__ a, const float* __restrict__ b,
    const float* __restrict__ c, const float* __restrict__ d,
    bf16* __restrict__ out) {
  int i = (blockIdx.x * 256 + threadIdx.x) * 4;
  const float* srcs[4] = {a, b, c, d};
#pragma unroll
  for (int w = 0; w < 4; ++w) {
    f32x4 x = *(const f32x4*)(srcs[w] + i);
    bf16x4 v;
    v[0] = (bf16)x[0]; v[1] = (bf16)x[1]; v[2] = (bf16)x[2]; v[3] = (bf16)x[3];
    *(bf16x4*)(out + (size_t)w * (D_ * D_) + i) = v;
  }
}

// ---------------------------------------------------------------------------
// f32 -> bf16 input conversion (one [B*S*D] array), vectorized 8 elems/thread
// ---------------------------------------------------------------------------
__global__ __launch_bounds__(256) void convert_in(const float* __restrict__ in,
                                                  bf16* __restrict__ out) {
  const int n8 = (B_ * S_ * D_) / 8;
  for (int i = blockIdx.x * 256 + threadIdx.x; i < n8; i += gridDim.x * 256) {
    f32x4 x0 = *(const f32x4*)(in + (size_t)i * 8);
    f32x4 x1 = *(const f32x4*)(in + (size_t)i * 8 + 4);
    bf16x8 v;
    v[0] = (bf16)x0[0]; v[1] = (bf16)x0[1]; v[2] = (bf16)x0[2]; v[3] = (bf16)x0[3];
    v[4] = (bf16)x1[0]; v[5] = (bf16)x1[1]; v[6] = (bf16)x1[2]; v[7] = (bf16)x1[3];
    *(bf16x8*)(out + (size_t)i * 8) = v;
  }
}

// ---------------------------------------------------------------------------
// bf16 GEMM: C[8192][1024] = A[8192][1024] @ W[1024][1024]^T + bias
// 128x128 tile, BK=64, 4 waves (2x2). A and W both staged via global_load_lds.
// MODE 0: bf16 head layout [B][H][S][HD], scaled by oscale (Q / K)
// MODE 1: bf16 transposed head layout [B][H][HD][S]  (V)
// MODE 2: f32 row-major [8192][1024] (final output)
// ---------------------------------------------------------------------------
template <int MODE>
__global__ __launch_bounds__(256, 2) void gemm_bf16(
    const bf16* __restrict__ A, const bf16* __restrict__ Wb,
    const float* __restrict__ bias, void* __restrict__ Out, float oscale) {
  __shared__ alignas(128) char lds[32768];  // A: [0,16K)  B: [16K,32K)
  const int tid = threadIdx.x;
  const int lane = tid & 63;
  const int wave = tid >> 6;
  const int m0 = blockIdx.x * 128;
  const int n0 = blockIdx.y * 128;
  const int wr = wave >> 1, wc = wave & 1;

  f32x4 acc[4][4] = {};

  for (int kt = 0; kt < 16; ++kt) {
    const int k0 = kt * 64;
#pragma unroll
    for (int j = 0; j < 4; ++j) {
      int slot = j * 256 + tid;
      int row = slot >> 3, kb = slot & 7;
      gload_lds16(A + (size_t)(m0 + row) * D_ + k0 + ((kb ^ (row & 7)) << 3),
                  lds + j * 4096 + wave * 1024);
    }
#pragma unroll
    for (int j = 0; j < 4; ++j) {
      int slot = j * 256 + tid;
      int row = slot >> 3, kb = slot & 7;
      gload_lds16(Wb + (size_t)(n0 + row) * D_ + k0 + ((kb ^ (row & 7)) << 3),
                  lds + 16384 + j * 4096 + wave * 1024);
    }
    __syncthreads();
#pragma unroll
    for (int ks = 0; ks < 2; ++ks) {
      bf16x8 af[4], bfr[4];
#pragma unroll
      for (int f = 0; f < 4; ++f) {
        int ar = wr * 64 + f * 16 + (lane & 15);
        af[f] = *(const bf16x8*)(lds + ar * 128 +
                                 (((ks * 4 + (lane >> 4)) ^ (ar & 7)) << 4));
        int br = wc * 64 + f * 16 + (lane & 15);
        bfr[f] = *(const bf16x8*)(lds + 16384 + br * 128 +
                                  (((ks * 4 + (lane >> 4)) ^ (br & 7)) << 4));
      }
#pragma unroll
      for (int i = 0; i < 4; ++i)
#pragma unroll
        for (int j = 0; j < 4; ++j)
          acc[i][j] = mfma16(af[i], bfr[j], acc[i][j]);
    }
    __syncthreads();
  }

  // epilogue. C frag mapping: col = lane&15, row = (lane>>4)*4 + r.
#pragma unroll
  for (int j = 0; j < 4; ++j) {
    const int col = n0 + wc * 64 + j * 16 + (lane & 15);
    const float bv_ = bias[col];
    const int h = col >> 6, hd = col & 63;
#pragma unroll
    for (int i = 0; i < 4; ++i) {
      const int row0 = m0 + wr * 64 + i * 16 + ((lane >> 4) << 2);
      if (MODE == 2) {
        float* O = (float*)Out;
#pragma unroll
        for (int r = 0; r < 4; ++r)
          O[(size_t)(row0 + r) * D_ + col] = acc[i][j][r] + bv_;
      } else if (MODE == 0) {  // head layout [B][H][S][HD]
        bf16* O = (bf16*)Out;
#pragma unroll
        for (int r = 0; r < 4; ++r) {
          int row = row0 + r;
          int b = row >> 11, s = row & (S_ - 1);
          O[(((size_t)(b * H_ + h) * S_ + s) << 6) + hd] =
              (bf16)((acc[i][j][r] + bv_) * oscale);
        }
      } else {  // MODE 1: V transposed [B][H][HD][S]; acc rows s-contiguous
        bf16* O = (bf16*)Out;
        int b = row0 >> 11, s0 = row0 & (S_ - 1);
        bf16x4 pk;
#pragma unroll
        for (int r = 0; r < 4; ++r) pk[r] = (bf16)(acc[i][j][r] + bv_);
        *(bf16x4*)(O + ((size_t)(b * H_ + h) * HD_ + hd) * S_ + s0) = pk;
      }
    }
  }
}

// ---------------------------------------------------------------------------
// Attention v9: v6 dual-pipe body + T4 counted-vmcnt 3-buffer pipeline.
// 4 waves x 64 q = 256 q/block; grid 512 1D (bh = bid&63 -> XCD co-location).
// Prefetch runs TWO tiles ahead into 3 rotating 16KB buffers; per tile each
// wave issues its 4 global_load_lds for t+2, computes on tile t, then
// s_waitcnt vmcnt(4) (waits only t+1's loads; t+2's stay in flight ACROSS the
// raw s_barrier — never vmcnt(0) in the loop). sched_barrier(0) fences the
// inline-asm wait (rule: compiler hoists past asm waitcnt otherwise).
// ---------------------------------------------------------------------------
__global__ __launch_bounds__(256, 2) void attn_kernel(
    const bf16* __restrict__ Qh, const bf16* __restrict__ Kh,
    const bf16* __restrict__ Vt, bf16* __restrict__ AO) {
  // frag-major per buffer: K frags 0..7 (kb*4+ks) at [0,8K); V frags 8..15
  // (kslot*2+ht) at [8K,16K). 3 buffers rotate.
  __shared__ alignas(128) char lds[49152];
  const int tid = threadIdx.x, lane = tid & 63, wave = tid >> 6;
  const int hi = lane >> 5, l31 = lane & 31;
  const int bid = blockIdx.x;
  const int bh = bid & 63;   // XCD co-location: xcd = bid%8 = bh%8
  const int qb = bid >> 6;   // [0,8)
  const int q0 = qb * 256 + wave * 64;
  const bf16* Qb = Qh + (size_t)bh * S_ * HD_;
  const bf16* Kb = Kh + (size_t)bh * S_ * HD_;
  const bf16* Vb = Vt + (size_t)bh * HD_ * S_;

  // Q B-frags (col q = l31, k = hd = ks*16 + hi*8 + j); 2 q-groups.
  bf16x8 qf[2][4];
#pragma unroll
  for (int qg = 0; qg < 2; ++qg)
#pragma unroll
    for (int ks = 0; ks < 4; ++ks)
      qf[qg][ks] = *(const bf16x8*)(Qb + (size_t)(q0 + qg * 32 + l31) * HD_ +
                                    ks * 16 + hi * 8);
  // Drain Q loads so the manual vmcnt bookkeeping below stays exact.
  asm volatile("s_waitcnt vmcnt(0)" ::: "memory");

  // staging: wave w (of 4) stages frags {w, 4+w, 8+w, 12+w}
  const bf16* gs[4];
  int lo_[4], ginc[4];
#pragma unroll
  for (int j = 0; j < 4; ++j) {
    int f = j * 4 + wave;
    lo_[j] = f * 1024;
    if (f < 8) {  // K frag: kb = f>>2, ks = f&3
      gs[j] = Kb + (size_t)((f >> 2) * 32 + l31) * HD_ + (f & 3) * 16 + hi * 8;
      ginc[j] = 64 * HD_;
    } else {  // V frag g=f-8: ht = g&1, kslot = g>>1
      int g = f - 8;
      gs[j] = Vb + (size_t)((g & 1) * 32 + l31) * S_ + (g >> 1) * 16 + hi * 8;
      ginc[j] = 64;
    }
  }

  f32x16 oacc[2][2] = {};     // [qg][ht]
  float dl[2] = {0.f, 0.f};   // per-lane den partial per q-group

  char* b0 = lds;
  char* b1 = lds + 16384;
  char* b2 = lds + 32768;

  // prologue: stage tile 0 -> b0, tile 1 -> b1 (8 loads in flight per wave)
#pragma unroll
  for (int j = 0; j < 4; ++j) {
    gload_lds16(gs[j], b0 + lo_[j]);
    gs[j] += ginc[j];
  }
#pragma unroll
  for (int j = 0; j < 4; ++j) {
    gload_lds16(gs[j], b1 + lo_[j]);
    gs[j] += ginc[j];
  }
  asm volatile("s_waitcnt vmcnt(4)" ::: "memory");  // tile 0 resident
  __builtin_amdgcn_sched_barrier(0);
  __builtin_amdgcn_s_barrier();

  for (int t = 0; t < 32; ++t) {
    if (t < 30) {  // prefetch tile t+2 into b2; stays in flight across barrier
#pragma unroll
      for (int j = 0; j < 4; ++j) {
        gload_lds16(gs[j], b2 + lo_[j]);
        gs[j] += ginc[j];
      }
    }
    const char* kbuf = b0;
    const char* vbuf = b0 + 8192;

    // ---- QK issue for BOTH kv-blocks (16 mfma) ----
    f32x16 s[2][2];  // [kb][qg]
    s[0][0] = (f32x16){}; s[0][1] = (f32x16){};
    s[1][0] = (f32x16){}; s[1][1] = (f32x16){};
    __builtin_amdgcn_s_setprio(1);
#pragma unroll
    for (int kb = 0; kb < 2; ++kb)
#pragma unroll
      for (int ks = 0; ks < 4; ++ks) {
        bf16x8 kf = *(const bf16x8*)(kbuf + (kb * 4 + ks) * 1024 + lane * 16);
        s[kb][0] = mfma32(kf, qf[0][ks], s[kb][0]);
        s[kb][1] = mfma32(kf, qf[1][ks], s[kb][1]);
      }
    __builtin_amdgcn_s_setprio(0);

    // ---- per kv-block: softmax (VALU/TRANS) then PV (MFMA); softmax(kb1)
    // overlaps PV(kb0), softmax(kb0) overlaps QK tail. ----
#pragma unroll
    for (int kb = 0; kb < 2; ++kb) {
      bf16x8 pa[2][2];
#pragma unroll
      for (int qg = 0; qg < 2; ++qg) {
        float e[16];
#pragma unroll
        for (int r = 0; r < 16; ++r) e[r] = fexp2(s[kb][qg][r]);
        {
          float a0 = e[0] + e[1], a1 = e[2] + e[3], a2 = e[4] + e[5],
                a3 = e[6] + e[7], a4 = e[8] + e[9], a5 = e[10] + e[11],
                a6 = e[12] + e[13], a7 = e[14] + e[15];
          float b0_ = a0 + a1, b1_ = a2 + a3, b2_ = a4 + a5, b3_ = a6 + a7;
          dl[qg] += (b0_ + b1_) + (b2_ + b3_);
        }
        uint32_t w0 = cvt_pk(e[0], e[1]), w1 = cvt_pk(e[2], e[3]),
                 w2 = cvt_pk(e[4], e[5]), w3 = cvt_pk(e[6], e[7]),
                 w4 = cvt_pk(e[8], e[9]), w5 = cvt_pk(e[10], e[11]),
                 w6 = cvt_pk(e[12], e[13]), w7 = cvt_pk(e[14], e[15]);
        pl_swap(w0, w2);
        pl_swap(w1, w3);
        pl_swap(w4, w6);
        pl_swap(w5, w7);
        pa[qg][0] = pack4(w0, w1, w2, w3);  // kv 0..15 of this 32-block
        pa[qg][1] = pack4(w4, w5, w6, w7);  // kv 16..31
      }
      __builtin_amdgcn_s_setprio(1);
#pragma unroll
      for (int ht = 0; ht < 2; ++ht) {
        bf16x8 vf0 =
            *(const bf16x8*)(vbuf + ((kb * 2 + 0) * 2 + ht) * 1024 + lane * 16);
        oacc[0][ht] = mfma32(pa[0][0], vf0, oacc[0][ht]);
        oacc[1][ht] = mfma32(pa[1][0], vf0, oacc[1][ht]);
        bf16x8 vf1 =
            *(const bf16x8*)(vbuf + ((kb * 2 + 1) * 2 + ht) * 1024 + lane * 16);
        oacc[0][ht] = mfma32(pa[0][1], vf1, oacc[0][ht]);
        oacc[1][ht] = mfma32(pa[1][1], vf1, oacc[1][ht]);
      }
      __builtin_amdgcn_s_setprio(0);
    }

    // counted wait: only tile t+1's 4 loads must land; t+2's stay in flight.
    if (t < 30)
      asm volatile("s_waitcnt vmcnt(4)" ::: "memory");
    else
      asm volatile("s_waitcnt vmcnt(0)" ::: "memory");
    __builtin_amdgcn_sched_barrier(0);
    __builtin_amdgcn_s_barrier();
    char* tmp = b0; b0 = b1; b1 = b2; b2 = tmp;
  }

  // epilogue: den(q=l31) = dl(hi=0) + dl(hi=1); broadcast per oacc row.
  const int b = bh >> 4, h = bh & 15;
#pragma unroll
  for (int qg = 0; qg < 2; ++qg) {
    float d = dl[qg] + __shfl_xor(dl[qg], 32);
    float rden = 1.0f / d;
#pragma unroll
    for (int r = 0; r < 16; ++r) {
      int qr = (r & 3) + 8 * (r >> 2) + 4 * hi;  // q_local for this row
      float dr = __shfl(rden, qr);               // lane qr holds rden(q=qr)
      size_t base = ((size_t)(b * S_ + q0 + qg * 32 + qr)) * D_ + h * 64;
      AO[base + l31] = (bf16)(oacc[qg][0][r] * dr);
      AO[base + 32 + l31] = (bf16)(oacc[qg][1][r] * dr);
    }
  }
}

// ---------------------------------------------------------------------------
extern "C" void kernel_launch(void* const* d_in, const int* in_sizes, int n_in,
                              void* d_out, int out_size, void* d_ws,
                              size_t ws_size, hipStream_t stream) {
  (void)in_sizes; (void)n_in; (void)out_size; (void)ws_size;
  const float* q  = (const float*)d_in[0];
  const float* k  = (const float*)d_in[1];
  const float* v  = (const float*)d_in[2];
  const float* Wq = (const float*)d_in[3];
  const float* bq = (const float*)d_in[4];
  const float* Wk = (const float*)d_in[5];
  const float* bk = (const float*)d_in[6];
  const float* Wv = (const float*)d_in[7];
  const float* bv = (const float*)d_in[8];
  const float* Wo = (const float*)d_in[9];
  const float* bo = (const float*)d_in[10];

  bf16* ws = (bf16*)d_ws;
  const size_t WSZ = (size_t)D_ * D_;      // 1M elems per weight
  const size_t TSZ = (size_t)B_ * S_ * D_; // 8.39M elems per tensor
  bf16* Wqb = ws;
  bf16* Wkb = ws + WSZ;
  bf16* Wvb = ws + 2 * WSZ;
  bf16* Wob = ws + 3 * WSZ;
  bf16* Abf = ws + 4 * WSZ;  // bf16 copy of current input; later aliased by AO
  bf16* Qh  = Abf + TSZ;
  bf16* Kh  = Qh + TSZ;
  bf16* Vt  = Kh + TSZ;
  bf16* AO  = Abf;  // Abf dead after the 3rd projection GEMM

  convert_w<<<dim3(1024), dim3(256), 0, stream>>>(Wq, Wk, Wv, Wo, ws);
  dim3 gg(64, 8), bb(256);
  convert_in<<<dim3(2048), bb, 0, stream>>>(q, Abf);
  gemm_bf16<0><<<gg, bb, 0, stream>>>(Abf, Wqb, bq, Qh, QSCALE);
  convert_in<<<dim3(2048), bb, 0, stream>>>(k, Abf);
  gemm_bf16<0><<<gg, bb, 0, stream>>>(Abf, Wkb, bk, Kh, 1.0f);
  convert_in<<<dim3(2048), bb, 0, stream>>>(v, Abf);
  gemm_bf16<1><<<gg, bb, 0, stream>>>(Abf, Wvb, bv, Vt, 1.0f);
  attn_kernel<<<dim3(512), bb, 0, stream>>>(Qh, Kh, Vt, AO);
  gemm_bf16<2><<<gg, bb, 0, stream>>>(AO, Wob, bo, d_out, 1.0f);
}

// Round 11
// 189.413 us; speedup vs baseline: 4.6983x; 1.0433x over previous
//
#include <hip/hip_runtime.h>
#include <stdint.h>
#include <stddef.h>

#define B_ 4
#define S_ 2048
#define D_ 1024
#define H_ 16
#define HD_ 64

// exp(x/8) = 2^(x*0.125*log2(e)); folded into the Q projection output.
#define QSCALE 0.18033688f

typedef __bf16 bf16;
typedef __bf16 bf16x8 __attribute__((ext_vector_type(8)));
typedef __bf16 bf16x4 __attribute__((ext_vector_type(4)));
typedef float f32x4 __attribute__((ext_vector_type(4)));
typedef float f32x16 __attribute__((ext_vector_type(16)));
typedef uint32_t u32x4 __attribute__((ext_vector_type(4)));

__device__ __forceinline__ f32x4 mfma16(bf16x8 a, bf16x8 b, f32x4 c) {
  return __builtin_amdgcn_mfma_f32_16x16x32_bf16(a, b, c, 0, 0, 0);
}
__device__ __forceinline__ f32x16 mfma32(bf16x8 a, bf16x8 b, f32x16 c) {
  return __builtin_amdgcn_mfma_f32_32x32x16_bf16(a, b, c, 0, 0, 0);
}

__device__ __forceinline__ float fexp2(float x) {
#if __has_builtin(__builtin_amdgcn_exp2f)
  return __builtin_amdgcn_exp2f(x);
#else
  return exp2f(x);
#endif
}

// global -> LDS direct copy, 16B per lane. LDS dst is wave-uniform base
// (HW writes base + lane*16); global src is per-lane.
__device__ __forceinline__ void gload_lds16(const void* g, void* l) {
  __builtin_amdgcn_global_load_lds(
      (__attribute__((address_space(1))) uint32_t*)(uintptr_t)g,
      (__attribute__((address_space(3))) uint32_t*)l, 16, 0, 0);
}

__device__ __forceinline__ uint32_t cvt_pk(float lo, float hi) {
  uint32_t r;
  asm volatile("v_cvt_pk_bf16_f32 %0, %1, %2" : "=v"(r) : "v"(lo), "v"(hi));
  return r;
}

// v_permlane32_swap_b32: a' = lane<32 ? a : b[lane-32]; b' = lane<32 ? a[lane+32] : b
__device__ __forceinline__ void pl_swap(uint32_t& a, uint32_t& b) {
#if __has_builtin(__builtin_amdgcn_permlane32_swap)
  typedef int i32x2_t __attribute__((ext_vector_type(2)));
  i32x2_t r = __builtin_amdgcn_permlane32_swap((int)a, (int)b, false, false);
  a = (uint32_t)r[0];
  b = (uint32_t)r[1];
#else
  uint32_t pa_ = (uint32_t)__shfl_xor((int)a, 32);
  uint32_t pb_ = (uint32_t)__shfl_xor((int)b, 32);
  bool hi_ = (threadIdx.x & 32) != 0;
  uint32_t na = hi_ ? pb_ : a;
  uint32_t nb = hi_ ? b : pa_;
  a = na;
  b = nb;
#endif
}

__device__ __forceinline__ bf16x8 pack4(uint32_t a, uint32_t b, uint32_t c,
                                        uint32_t d) {
  u32x4 v = {a, b, c, d};
  return __builtin_bit_cast(bf16x8, v);
}

// ---------------------------------------------------------------------------
// f32 -> bf16 weight conversion (4 x [1024x1024])
// ---------------------------------------------------------------------------
__global__ __launch_bounds__(256) void convert_w(
    const float* __restrict__ a, const float* __restrict__ b,
    const float* __restrict__ c, const float* __restrict__ d,
    bf16* __restrict__ out) {
  int i = (blockIdx.x * 256 + threadIdx.x) * 4;
  const float* srcs[4] = {a, b, c, d};
#pragma unroll
  for (int w = 0; w < 4; ++w) {
    f32x4 x = *(const f32x4*)(srcs[w] + i);
    bf16x4 v;
    v[0] = (bf16)x[0]; v[1] = (bf16)x[1]; v[2] = (bf16)x[2]; v[3] = (bf16)x[3];
    *(bf16x4*)(out + (size_t)w * (D_ * D_) + i) = v;
  }
}

// ---------------------------------------------------------------------------
// f32 -> bf16 input conversion, single tensor (fallback path)
// ---------------------------------------------------------------------------
__global__ __launch_bounds__(256) void convert_in(const float* __restrict__ in,
                                                  bf16* __restrict__ out) {
  const int n8 = (B_ * S_ * D_) / 8;
  for (int i = blockIdx.x * 256 + threadIdx.x; i < n8; i += gridDim.x * 256) {
    f32x4 x0 = *(const f32x4*)(in + (size_t)i * 8);
    f32x4 x1 = *(const f32x4*)(in + (size_t)i * 8 + 4);
    bf16x8 v;
    v[0] = (bf16)x0[0]; v[1] = (bf16)x0[1]; v[2] = (bf16)x0[2]; v[3] = (bf16)x0[3];
    v[4] = (bf16)x1[0]; v[5] = (bf16)x1[1]; v[6] = (bf16)x1[2]; v[7] = (bf16)x1[3];
    *(bf16x8*)(out + (size_t)i * 8) = v;
  }
}

// ---------------------------------------------------------------------------
// f32 -> bf16 conversion of ALL THREE inputs in one launch.
// n8 = B*S*D/8 = 2^20, so tensor select is shift/mask. out is [3][B*S*D].
// ---------------------------------------------------------------------------
__global__ __launch_bounds__(256) void convert_in3(
    const float* __restrict__ a, const float* __restrict__ b,
    const float* __restrict__ c, bf16* __restrict__ out) {
  const int n8 = (B_ * S_ * D_) / 8;  // 1<<20
  for (int i = blockIdx.x * 256 + threadIdx.x; i < 3 * n8;
       i += gridDim.x * 256) {
    int t = i >> 20;
    int off = i & (n8 - 1);
    const float* src = t == 0 ? a : (t == 1 ? b : c);
    f32x4 x0 = *(const f32x4*)(src + (size_t)off * 8);
    f32x4 x1 = *(const f32x4*)(src + (size_t)off * 8 + 4);
    bf16x8 v;
    v[0] = (bf16)x0[0]; v[1] = (bf16)x0[1]; v[2] = (bf16)x0[2]; v[3] = (bf16)x0[3];
    v[4] = (bf16)x1[0]; v[5] = (bf16)x1[1]; v[6] = (bf16)x1[2]; v[7] = (bf16)x1[3];
    *(bf16x8*)(out + (size_t)i * 8) = v;
  }
}

// ---------------------------------------------------------------------------
// bf16 GEMM: C[8192][1024] = A[8192][1024] @ W[1024][1024]^T + bias
// 128x128 tile, BK=64, 4 waves (2x2). A and W both staged via global_load_lds.
// MODE 0: bf16 head layout [B][H][S][HD], scaled by oscale (Q / K)
// MODE 1: bf16 transposed head layout [B][H][HD][S]  (V)
// MODE 2: f32 row-major [8192][1024] (final output)
// ---------------------------------------------------------------------------
template <int MODE>
__global__ __launch_bounds__(256, 2) void gemm_bf16(
    const bf16* __restrict__ A, const bf16* __restrict__ Wb,
    const float* __restrict__ bias, void* __restrict__ Out, float oscale) {
  __shared__ alignas(128) char lds[32768];  // A: [0,16K)  B: [16K,32K)
  const int tid = threadIdx.x;
  const int lane = tid & 63;
  const int wave = tid >> 6;
  const int m0 = blockIdx.x * 128;
  const int n0 = blockIdx.y * 128;
  const int wr = wave >> 1, wc = wave & 1;

  f32x4 acc[4][4] = {};

  for (int kt = 0; kt < 16; ++kt) {
    const int k0 = kt * 64;
#pragma unroll
    for (int j = 0; j < 4; ++j) {
      int slot = j * 256 + tid;
      int row = slot >> 3, kb = slot & 7;
      gload_lds16(A + (size_t)(m0 + row) * D_ + k0 + ((kb ^ (row & 7)) << 3),
                  lds + j * 4096 + wave * 1024);
    }
#pragma unroll
    for (int j = 0; j < 4; ++j) {
      int slot = j * 256 + tid;
      int row = slot >> 3, kb = slot & 7;
      gload_lds16(Wb + (size_t)(n0 + row) * D_ + k0 + ((kb ^ (row & 7)) << 3),
                  lds + 16384 + j * 4096 + wave * 1024);
    }
    __syncthreads();
#pragma unroll
    for (int ks = 0; ks < 2; ++ks) {
      bf16x8 af[4], bfr[4];
#pragma unroll
      for (int f = 0; f < 4; ++f) {
        int ar = wr * 64 + f * 16 + (lane & 15);
        af[f] = *(const bf16x8*)(lds + ar * 128 +
                                 (((ks * 4 + (lane >> 4)) ^ (ar & 7)) << 4));
        int br = wc * 64 + f * 16 + (lane & 15);
        bfr[f] = *(const bf16x8*)(lds + 16384 + br * 128 +
                                  (((ks * 4 + (lane >> 4)) ^ (br & 7)) << 4));
      }
#pragma unroll
      for (int i = 0; i < 4; ++i)
#pragma unroll
        for (int j = 0; j < 4; ++j)
          acc[i][j] = mfma16(af[i], bfr[j], acc[i][j]);
    }
    __syncthreads();
  }

  // epilogue. C frag mapping: col = lane&15, row = (lane>>4)*4 + r.
#pragma unroll
  for (int j = 0; j < 4; ++j) {
    const int col = n0 + wc * 64 + j * 16 + (lane & 15);
    const float bv_ = bias[col];
    const int h = col >> 6, hd = col & 63;
#pragma unroll
    for (int i = 0; i < 4; ++i) {
      const int row0 = m0 + wr * 64 + i * 16 + ((lane >> 4) << 2);
      if (MODE == 2) {
        float* O = (float*)Out;
#pragma unroll
        for (int r = 0; r < 4; ++r)
          O[(size_t)(row0 + r) * D_ + col] = acc[i][j][r] + bv_;
      } else if (MODE == 0) {  // head layout [B][H][S][HD]
        bf16* O = (bf16*)Out;
#pragma unroll
        for (int r = 0; r < 4; ++r) {
          int row = row0 + r;
          int b = row >> 11, s = row & (S_ - 1);
          O[(((size_t)(b * H_ + h) * S_ + s) << 6) + hd] =
              (bf16)((acc[i][j][r] + bv_) * oscale);
        }
      } else {  // MODE 1: V transposed [B][H][HD][S]; acc rows s-contiguous
        bf16* O = (bf16*)Out;
        int b = row0 >> 11, s0 = row0 & (S_ - 1);
        bf16x4 pk;
#pragma unroll
        for (int r = 0; r < 4; ++r) pk[r] = (bf16)(acc[i][j][r] + bv_);
        *(bf16x4*)(O + ((size_t)(b * H_ + h) * HD_ + hd) * S_ + s0) = pk;
      }
    }
  }
}

// ---------------------------------------------------------------------------
// Fused QKV projection GEMM (bf16 A), z = blockIdx.z in {Q,K,V}.
// Same tile body as gemm_bf16; 1536 blocks -> ~5 blocks/CU so the per-K-step
// staging drains overlap across co-resident blocks.
// z==0: Q head layout, scaled. z==1: K head layout. z==2: V transposed.
// ---------------------------------------------------------------------------
__global__ __launch_bounds__(256, 2) void gemm_qkv3(
    const bf16* __restrict__ Abase, const bf16* __restrict__ Wbase,
    const float* __restrict__ bq, const float* __restrict__ bk,
    const float* __restrict__ bv, bf16* __restrict__ Outbase) {
  __shared__ alignas(128) char lds[32768];
  const int tid = threadIdx.x;
  const int lane = tid & 63;
  const int wave = tid >> 6;
  const int m0 = blockIdx.x * 128;
  const int n0 = blockIdx.y * 128;
  const int wr = wave >> 1, wc = wave & 1;
  const int z = blockIdx.z;
  const bf16* A = Abase + (size_t)z * ((size_t)B_ * S_ * D_);
  const bf16* Wb = Wbase + (size_t)z * (D_ * D_);
  const float* bias = z == 0 ? bq : (z == 1 ? bk : bv);
  bf16* Out = Outbase + (size_t)z * ((size_t)B_ * S_ * D_);
  const float oscale = (z == 0) ? QSCALE : 1.0f;

  f32x4 acc[4][4] = {};

  for (int kt = 0; kt < 16; ++kt) {
    const int k0 = kt * 64;
#pragma unroll
    for (int j = 0; j < 4; ++j) {
      int slot = j * 256 + tid;
      int row = slot >> 3, kb = slot & 7;
      gload_lds16(A + (size_t)(m0 + row) * D_ + k0 + ((kb ^ (row & 7)) << 3),
                  lds + j * 4096 + wave * 1024);
    }
#pragma unroll
    for (int j = 0; j < 4; ++j) {
      int slot = j * 256 + tid;
      int row = slot >> 3, kb = slot & 7;
      gload_lds16(Wb + (size_t)(n0 + row) * D_ + k0 + ((kb ^ (row & 7)) << 3),
                  lds + 16384 + j * 4096 + wave * 1024);
    }
    __syncthreads();
#pragma unroll
    for (int ks = 0; ks < 2; ++ks) {
      bf16x8 af[4], bfr[4];
#pragma unroll
      for (int f = 0; f < 4; ++f) {
        int ar = wr * 64 + f * 16 + (lane & 15);
        af[f] = *(const bf16x8*)(lds + ar * 128 +
                                 (((ks * 4 + (lane >> 4)) ^ (ar & 7)) << 4));
        int br = wc * 64 + f * 16 + (lane & 15);
        bfr[f] = *(const bf16x8*)(lds + 16384 + br * 128 +
                                  (((ks * 4 + (lane >> 4)) ^ (br & 7)) << 4));
      }
#pragma unroll
      for (int i = 0; i < 4; ++i)
#pragma unroll
        for (int j = 0; j < 4; ++j)
          acc[i][j] = mfma16(af[i], bfr[j], acc[i][j]);
    }
    __syncthreads();
  }

#pragma unroll
  for (int j = 0; j < 4; ++j) {
    const int col = n0 + wc * 64 + j * 16 + (lane & 15);
    const float bv_ = bias[col];
    const int h = col >> 6, hd = col & 63;
#pragma unroll
    for (int i = 0; i < 4; ++i) {
      const int row0 = m0 + wr * 64 + i * 16 + ((lane >> 4) << 2);
      if (z != 2) {  // head layout [B][H][S][HD], Q scaled
#pragma unroll
        for (int r = 0; r < 4; ++r) {
          int row = row0 + r;
          int b = row >> 11, s = row & (S_ - 1);
          Out[(((size_t)(b * H_ + h) * S_ + s) << 6) + hd] =
              (bf16)((acc[i][j][r] + bv_) * oscale);
        }
      } else {  // V transposed [B][H][HD][S]; acc rows s-contiguous
        int b = row0 >> 11, s0 = row0 & (S_ - 1);
        bf16x4 pk;
#pragma unroll
        for (int r = 0; r < 4; ++r) pk[r] = (bf16)(acc[i][j][r] + bv_);
        *(bf16x4*)(Out + ((size_t)(b * H_ + h) * HD_ + hd) * S_ + s0) = pk;
      }
    }
  }
}

// ---------------------------------------------------------------------------
// Attention (round-7 v6 config, best measured: 78 us): within-wave dual-pipe.
// 4 waves x 64 q = 256 q/block; grid 512 1D (bh = bid&63 -> XCD co-location).
// Per tile: issue QK(kb0)+QK(kb1); softmax(kb0) on VALU overlaps QK(kb1);
// PV(kb0) overlaps softmax(kb1); PV(kb1). Shared zero-C register for the
// per-tile s init (no per-tile v_mov block).
// ---------------------------------------------------------------------------
__global__ __launch_bounds__(256, 2) void attn_kernel(
    const bf16* __restrict__ Qh, const bf16* __restrict__ Kh,
    const bf16* __restrict__ Vt, bf16* __restrict__ AO) {
  // frag-major LDS: K frags 0..7 (kb*4+ks) at [0,8K); V frags 8..15
  // (kslot*2+ht) at [8K,16K); x2 double buffer.
  __shared__ alignas(128) char lds[2][16384];
  const int tid = threadIdx.x, lane = tid & 63, wave = tid >> 6;
  const int hi = lane >> 5, l31 = lane & 31;
  const int bid = blockIdx.x;
  const int bh = bid & 63;   // XCD co-location: xcd = bid%8 = bh%8
  const int qb = bid >> 6;   // [0,8)
  const int q0 = qb * 256 + wave * 64;
  const bf16* Qb = Qh + (size_t)bh * S_ * HD_;
  const bf16* Kb = Kh + (size_t)bh * S_ * HD_;
  const bf16* Vb = Vt + (size_t)bh * HD_ * S_;

  // Q B-frags (col q = l31, k = hd = ks*16 + hi*8 + j); 2 q-groups.
  bf16x8 qf[2][4];
#pragma unroll
  for (int qg = 0; qg < 2; ++qg)
#pragma unroll
    for (int ks = 0; ks < 4; ++ks)
      qf[qg][ks] = *(const bf16x8*)(Qb + (size_t)(q0 + qg * 32 + l31) * HD_ +
                                    ks * 16 + hi * 8);

  // staging: wave w (of 4) stages frags {w, 4+w, 8+w, 12+w}
  const bf16* gs[4];
  int lo_[4], ginc[4];
#pragma unroll
  for (int j = 0; j < 4; ++j) {
    int f = j * 4 + wave;
    lo_[j] = f * 1024;
    if (f < 8) {  // K frag: kb = f>>2, ks = f&3
      gs[j] = Kb + (size_t)((f >> 2) * 32 + l31) * HD_ + (f & 3) * 16 + hi * 8;
      ginc[j] = 64 * HD_;
    } else {  // V frag g=f-8: ht = g&1, kslot = g>>1
      int g = f - 8;
      gs[j] = Vb + (size_t)((g & 1) * 32 + l31) * S_ + (g >> 1) * 16 + hi * 8;
      ginc[j] = 64;
    }
  }

  f32x16 oacc[2][2] = {};     // [qg][ht]
  float dl[2] = {0.f, 0.f};   // per-lane den partial per q-group
  const f32x16 z16 = {};      // shared zero C-operand

  // prologue: stage tile 0 into buf 0
#pragma unroll
  for (int j = 0; j < 4; ++j) {
    gload_lds16(gs[j], &lds[0][lo_[j]]);
    gs[j] += ginc[j];
  }
  __syncthreads();

  for (int t = 0; t < 32; ++t) {
    const int cur = t & 1;
    if (t < 31) {  // prefetch next tile; latency hides under compute
#pragma unroll
      for (int j = 0; j < 4; ++j) {
        gload_lds16(gs[j], &lds[cur ^ 1][lo_[j]]);
        gs[j] += ginc[j];
      }
    }
    const char* kbuf = lds[cur];
    const char* vbuf = lds[cur] + 8192;

    // ---- QK issue for BOTH kv-blocks (16 mfma) ----
    f32x16 s[2][2];  // [kb][qg]
    __builtin_amdgcn_s_setprio(1);
#pragma unroll
    for (int kb = 0; kb < 2; ++kb)
#pragma unroll
      for (int ks = 0; ks < 4; ++ks) {
        bf16x8 kf = *(const bf16x8*)(kbuf + (kb * 4 + ks) * 1024 + lane * 16);
        if (ks == 0) {
          s[kb][0] = mfma32(kf, qf[0][0], z16);
          s[kb][1] = mfma32(kf, qf[1][0], z16);
        } else {
          s[kb][0] = mfma32(kf, qf[0][ks], s[kb][0]);
          s[kb][1] = mfma32(kf, qf[1][ks], s[kb][1]);
        }
      }
    __builtin_amdgcn_s_setprio(0);

    // ---- per kv-block: softmax (VALU/TRANS) then PV (MFMA); softmax(kb1)
    // overlaps PV(kb0), softmax(kb0) overlaps QK tail. ----
#pragma unroll
    for (int kb = 0; kb < 2; ++kb) {
      bf16x8 pa[2][2];
#pragma unroll
      for (int qg = 0; qg < 2; ++qg) {
        float e[16];
#pragma unroll
        for (int r = 0; r < 16; ++r) e[r] = fexp2(s[kb][qg][r]);
        {
          float a0 = e[0] + e[1], a1 = e[2] + e[3], a2 = e[4] + e[5],
                a3 = e[6] + e[7], a4 = e[8] + e[9], a5 = e[10] + e[11],
                a6 = e[12] + e[13], a7 = e[14] + e[15];
          float b0_ = a0 + a1, b1_ = a2 + a3, b2_ = a4 + a5, b3_ = a6 + a7;
          dl[qg] += (b0_ + b1_) + (b2_ + b3_);
        }
        uint32_t w0 = cvt_pk(e[0], e[1]), w1 = cvt_pk(e[2], e[3]),
                 w2 = cvt_pk(e[4], e[5]), w3 = cvt_pk(e[6], e[7]),
                 w4 = cvt_pk(e[8], e[9]), w5 = cvt_pk(e[10], e[11]),
                 w6 = cvt_pk(e[12], e[13]), w7 = cvt_pk(e[14], e[15]);
        pl_swap(w0, w2);
        pl_swap(w1, w3);
        pl_swap(w4, w6);
        pl_swap(w5, w7);
        pa[qg][0] = pack4(w0, w1, w2, w3);  // kv 0..15 of this 32-block
        pa[qg][1] = pack4(w4, w5, w6, w7);  // kv 16..31
      }
      __builtin_amdgcn_s_setprio(1);
#pragma unroll
      for (int ht = 0; ht < 2; ++ht) {
        bf16x8 vf0 =
            *(const bf16x8*)(vbuf + ((kb * 2 + 0) * 2 + ht) * 1024 + lane * 16);
        oacc[0][ht] = mfma32(pa[0][0], vf0, oacc[0][ht]);
        oacc[1][ht] = mfma32(pa[1][0], vf0, oacc[1][ht]);
        bf16x8 vf1 =
            *(const bf16x8*)(vbuf + ((kb * 2 + 1) * 2 + ht) * 1024 + lane * 16);
        oacc[0][ht] = mfma32(pa[0][1], vf1, oacc[0][ht]);
        oacc[1][ht] = mfma32(pa[1][1], vf1, oacc[1][ht]);
      }
      __builtin_amdgcn_s_setprio(0);
    }
    __syncthreads();  // next tile staged; cur buffer free for overwrite
  }

  // epilogue: den(q=l31) = dl(hi=0) + dl(hi=1); broadcast per oacc row.
  const int b = bh >> 4, h = bh & 15;
#pragma unroll
  for (int qg = 0; qg < 2; ++qg) {
    float d = dl[qg] + __shfl_xor(dl[qg], 32);
    float rden = 1.0f / d;
#pragma unroll
    for (int r = 0; r < 16; ++r) {
      int qr = (r & 3) + 8 * (r >> 2) + 4 * hi;  // q_local for this row
      float dr = __shfl(rden, qr);               // lane qr holds rden(q=qr)
      size_t base = ((size_t)(b * S_ + q0 + qg * 32 + qr)) * D_ + h * 64;
      AO[base + l31] = (bf16)(oacc[qg][0][r] * dr);
      AO[base + 32 + l31] = (bf16)(oacc[qg][1][r] * dr);
    }
  }
}

// ---------------------------------------------------------------------------
extern "C" void kernel_launch(void* const* d_in, const int* in_sizes, int n_in,
                              void* d_out, int out_size, void* d_ws,
                              size_t ws_size, hipStream_t stream) {
  (void)in_sizes; (void)n_in; (void)out_size;
  const float* q  = (const float*)d_in[0];
  const float* k  = (const float*)d_in[1];
  const float* v  = (const float*)d_in[2];
  const float* Wq = (const float*)d_in[3];
  const float* bq = (const float*)d_in[4];
  const float* Wk = (const float*)d_in[5];
  const float* bk = (const float*)d_in[6];
  const float* Wv = (const float*)d_in[7];
  const float* bv = (const float*)d_in[8];
  const float* Wo = (const float*)d_in[9];
  const float* bo = (const float*)d_in[10];

  bf16* ws = (bf16*)d_ws;
  const size_t WSZ = (size_t)D_ * D_;      // 1M elems per weight
  const size_t TSZ = (size_t)B_ * S_ * D_; // 8.39M elems per tensor
  bf16* Wqkv = ws;           // Wq,Wk,Wv bf16 contiguous (z-indexed)
  bf16* Wob  = ws + 3 * WSZ;

  dim3 gg(64, 8), bb(256);
  convert_w<<<dim3(1024), bb, 0, stream>>>(Wq, Wk, Wv, Wo, ws);

  const size_t need_fused = (4 * WSZ + 6 * TSZ) * sizeof(bf16);  // ~109 MB
  if (ws_size >= need_fused) {
    // Fused path: all three inputs converted in one launch; QKV GEMMs in one
    // z=3 launch (1536 blocks -> ~5 blocks/CU).
    bf16* Abf3 = ws + 4 * WSZ;       // [3][TSZ]
    bf16* QKV  = Abf3 + 3 * TSZ;     // Qh, Kh, Vt contiguous
    bf16* AO   = Abf3;               // Abf3 dead after projections
    convert_in3<<<dim3(4096), bb, 0, stream>>>(q, k, v, Abf3);
    gemm_qkv3<<<dim3(64, 8, 3), bb, 0, stream>>>(Abf3, Wqkv, bq, bk, bv, QKV);
    attn_kernel<<<dim3(512), bb, 0, stream>>>(QKV, QKV + TSZ, QKV + 2 * TSZ,
                                              AO);
    gemm_bf16<2><<<gg, bb, 0, stream>>>(AO, Wob, bo, d_out, 1.0f);
  } else {
    // Sequential fallback (round-7 layout, 75.5 MB)
    bf16* Abf = ws + 4 * WSZ;
    bf16* Qh  = Abf + TSZ;
    bf16* Kh  = Qh + TSZ;
    bf16* Vt  = Kh + TSZ;
    bf16* AO  = Abf;
    convert_in<<<dim3(2048), bb, 0, stream>>>(q, Abf);
    gemm_bf16<0><<<gg, bb, 0, stream>>>(Abf, Wqkv, bq, Qh, QSCALE);
    convert_in<<<dim3(2048), bb, 0, stream>>>(k, Abf);
    gemm_bf16<0><<<gg, bb, 0, stream>>>(Abf, Wqkv + WSZ, bk, Kh, 1.0f);
    convert_in<<<dim3(2048), bb, 0, stream>>>(v, Abf);
    gemm_bf16<1><<<gg, bb, 0, stream>>>(Abf, Wqkv + 2 * WSZ, bv, Vt, 1.0f);
    attn_kernel<<<dim3(512), bb, 0, stream>>>(Qh, Kh, Vt, AO);
    gemm_bf16<2><<<gg, bb, 0, stream>>>(AO, Wob, bo, d_out, 1.0f);
  }
}